// Round 1
// baseline (329.645 us; speedup 1.0000x reference)
//
#include <hip/hip_runtime.h>
#include <hip/hip_bf16.h>
#include <cstdint>
#include <cstddef>

#define BATCH 4
#define CIN   512
#define NPIX  1024
#define HEADS 16
#define DH    32
#define DATTN 512
#define O_QKV 1536

// ---------------------------------------------------------------------------
// Generic per-pixel GEMM:  out[b][o][n] = sum_k w[o][k] * in[b][k][n] + bias[o]
// in:  [B][K][NPIX]   w: [O][K] row-major   out: [B][O][NPIX]
// Tile: 64 (o) x 64 (n), BK=16. 256 threads, each computes 4x4.
// ---------------------------------------------------------------------------
__global__ __launch_bounds__(256) void gemm_pix(const float* __restrict__ in,
                                                const float* __restrict__ w,
                                                const float* __restrict__ bias,
                                                float* __restrict__ out,
                                                int O, int K) {
  __shared__ float sA[16][64];  // [kk][o]
  __shared__ float sB[16][64];  // [kk][n]
  const int t  = threadIdx.x;
  const int b  = blockIdx.z;
  const int o0 = blockIdx.y * 64;
  const int n0 = blockIdx.x * 64;
  const int tx = t & 15, ty = t >> 4;
  const float* inb = in + (size_t)b * K * NPIX;

  float acc[4][4] = {{0.f}};

  const int oA  = t >> 2;        // 0..63
  const int kkA = (t & 3) << 2;  // 0,4,8,12
  const int kkB = t >> 4;        // 0..15
  const int nB  = (t & 15) << 2; // 0..60

  for (int k = 0; k < K; k += 16) {
    // stage W tile [64 o][16 k] -> sA[kk][o]
    float4 a4 = *reinterpret_cast<const float4*>(&w[(size_t)(o0 + oA) * K + k + kkA]);
    sA[kkA + 0][oA] = a4.x;
    sA[kkA + 1][oA] = a4.y;
    sA[kkA + 2][oA] = a4.z;
    sA[kkA + 3][oA] = a4.w;
    // stage input tile [16 k][64 n]
    *reinterpret_cast<float4*>(&sB[kkB][nB]) =
        *reinterpret_cast<const float4*>(&inb[(size_t)(k + kkB) * NPIX + n0 + nB]);
    __syncthreads();

#pragma unroll
    for (int kk = 0; kk < 16; ++kk) {
      float4 av = *reinterpret_cast<const float4*>(&sA[kk][ty << 2]);
      float4 bv = *reinterpret_cast<const float4*>(&sB[kk][tx << 2]);
      acc[0][0] += av.x * bv.x; acc[0][1] += av.x * bv.y; acc[0][2] += av.x * bv.z; acc[0][3] += av.x * bv.w;
      acc[1][0] += av.y * bv.x; acc[1][1] += av.y * bv.y; acc[1][2] += av.y * bv.z; acc[1][3] += av.y * bv.w;
      acc[2][0] += av.z * bv.x; acc[2][1] += av.z * bv.y; acc[2][2] += av.z * bv.z; acc[2][3] += av.z * bv.w;
      acc[3][0] += av.w * bv.x; acc[3][1] += av.w * bv.y; acc[3][2] += av.w * bv.z; acc[3][3] += av.w * bv.w;
    }
    __syncthreads();
  }

#pragma unroll
  for (int i = 0; i < 4; ++i) {
    const int o = o0 + (ty << 2) + i;
    const float bb = bias[o];
    float4 r = make_float4(acc[i][0] + bb, acc[i][1] + bb, acc[i][2] + bb, acc[i][3] + bb);
    *reinterpret_cast<float4*>(&out[((size_t)b * O + o) * NPIX + n0 + (tx << 2)]) = r;
  }
}

// ---------------------------------------------------------------------------
// Flash-style attention.
// qkv layout: [B][1536][NPIX]; head h rows: q at h*96, k at h*96+32, v at h*96+64
// S[i,j] = scale * sum_d q[d,i] k[d,j] + rel[h,i,j]; P = softmax_j(S)
// aout[b][h*32+d][i] = sum_j P[i,j] v[d,j]
// Block: 256 threads, one (64-row i-tile, head, batch). j tiled by 64.
// Thread (tx,ty): S fragment rows i=ty*4..+3, cols j=tx*4..+3;
//                 out fragment rows i=ty*4..+3, d=tx*2..+1.
// ---------------------------------------------------------------------------
__global__ __launch_bounds__(256) void attn_kernel(const float* __restrict__ qkv,
                                                   const float* __restrict__ rel,
                                                   float* __restrict__ aout) {
  __shared__ float sQ[32][64];   // [d][i]
  __shared__ float sK[32][64];   // [d][j]
  __shared__ float sV[64][33];   // [j][d]  (+1 pad)
  __shared__ float sP[64][68];   // [i][j]  (+4 pad, keeps 16B align + bank spread)

  const int t  = threadIdx.x;
  const int i0 = blockIdx.x * 64;
  const int h  = blockIdx.y;
  const int b  = blockIdx.z;
  const int tx = t & 15, ty = t >> 4;
  const float scale = 0.17677669529663687f;  // 1/sqrt(32)

  const float* qb = qkv + ((size_t)b * O_QKV + h * 96) * NPIX;
  const float* kb = qb + (size_t)32 * NPIX;
  const float* vb = qb + (size_t)64 * NPIX;

  // load Q tile [32 d][64 i]
#pragma unroll
  for (int r = t; r < 512; r += 256) {
    int d = r >> 4, nn = (r & 15) << 2;
    *reinterpret_cast<float4*>(&sQ[d][nn]) =
        *reinterpret_cast<const float4*>(&qb[(size_t)d * NPIX + i0 + nn]);
  }

  float m_run[4], l_run[4], accd[4][2];
#pragma unroll
  for (int i = 0; i < 4; ++i) {
    m_run[i] = -1e30f; l_run[i] = 0.f; accd[i][0] = 0.f; accd[i][1] = 0.f;
  }

  for (int j0 = 0; j0 < NPIX; j0 += 64) {
    __syncthreads();  // protect K/V/P from previous iteration's readers (also covers Q load)
#pragma unroll
    for (int r = t; r < 512; r += 256) {
      int d = r >> 4, nn = (r & 15) << 2;
      *reinterpret_cast<float4*>(&sK[d][nn]) =
          *reinterpret_cast<const float4*>(&kb[(size_t)d * NPIX + j0 + nn]);
      float4 v4 = *reinterpret_cast<const float4*>(&vb[(size_t)d * NPIX + j0 + nn]);
      sV[nn + 0][d] = v4.x;
      sV[nn + 1][d] = v4.y;
      sV[nn + 2][d] = v4.z;
      sV[nn + 3][d] = v4.w;
    }
    __syncthreads();

    // ---- S = Q^T K (4x4 fragment) ----
    float s[4][4] = {{0.f}};
#pragma unroll
    for (int kk = 0; kk < 32; ++kk) {
      float4 av = *reinterpret_cast<const float4*>(&sQ[kk][ty << 2]);
      float4 bv = *reinterpret_cast<const float4*>(&sK[kk][tx << 2]);
      s[0][0] += av.x * bv.x; s[0][1] += av.x * bv.y; s[0][2] += av.x * bv.z; s[0][3] += av.x * bv.w;
      s[1][0] += av.y * bv.x; s[1][1] += av.y * bv.y; s[1][2] += av.y * bv.z; s[1][3] += av.y * bv.w;
      s[2][0] += av.z * bv.x; s[2][1] += av.z * bv.y; s[2][2] += av.z * bv.z; s[2][3] += av.z * bv.w;
      s[3][0] += av.w * bv.x; s[3][1] += av.w * bv.y; s[3][2] += av.w * bv.z; s[3][3] += av.w * bv.w;
    }

    // ---- scale + rel_pos ----
    {
      const float* relp = rel + ((size_t)h * NPIX + i0 + (ty << 2)) * NPIX + j0 + (tx << 2);
#pragma unroll
      for (int i = 0; i < 4; ++i) {
        float4 r4 = *reinterpret_cast<const float4*>(relp + (size_t)i * NPIX);
        s[i][0] = s[i][0] * scale + r4.x;
        s[i][1] = s[i][1] * scale + r4.y;
        s[i][2] = s[i][2] * scale + r4.z;
        s[i][3] = s[i][3] * scale + r4.w;
      }
    }

    // ---- online softmax ----
    float alpha[4];
#pragma unroll
    for (int i = 0; i < 4; ++i) {
      float mm = fmaxf(fmaxf(s[i][0], s[i][1]), fmaxf(s[i][2], s[i][3]));
#pragma unroll
      for (int off = 1; off < 16; off <<= 1) mm = fmaxf(mm, __shfl_xor(mm, off));
      float mnew = fmaxf(m_run[i], mm);
      alpha[i] = __expf(m_run[i] - mnew);
      m_run[i] = mnew;
      float ls = 0.f;
#pragma unroll
      for (int j = 0; j < 4; ++j) { s[i][j] = __expf(s[i][j] - mnew); ls += s[i][j]; }
#pragma unroll
      for (int off = 1; off < 16; off <<= 1) ls += __shfl_xor(ls, off);
      l_run[i] = l_run[i] * alpha[i] + ls;
    }

    // ---- write P tile ----
#pragma unroll
    for (int i = 0; i < 4; ++i) {
      *reinterpret_cast<float4*>(&sP[(ty << 2) + i][tx << 2]) =
          make_float4(s[i][0], s[i][1], s[i][2], s[i][3]);
    }
    __syncthreads();

    // ---- PV: accd[i][dd] += sum_j P[i,j] * V[j][d0+dd] ----
#pragma unroll
    for (int i = 0; i < 4; ++i) { accd[i][0] *= alpha[i]; accd[i][1] *= alpha[i]; }
    const int d0 = tx << 1;
#pragma unroll 8
    for (int j = 0; j < 64; ++j) {
      float v0 = sV[j][d0], v1 = sV[j][d0 + 1];
#pragma unroll
      for (int i = 0; i < 4; ++i) {
        float pv = sP[(ty << 2) + i][j];
        accd[i][0] += pv * v0;
        accd[i][1] += pv * v1;
      }
    }
  }

  // ---- epilogue: divide by l, write [B][512][NPIX] ----
#pragma unroll
  for (int i = 0; i < 4; ++i) {
    float inv = 1.f / l_run[i];
#pragma unroll
    for (int dd = 0; dd < 2; ++dd) {
      aout[((size_t)b * DATTN + h * DH + (tx << 1) + dd) * NPIX + i0 + (ty << 2) + i] =
          accd[i][dd] * inv;
    }
  }
}

extern "C" void kernel_launch(void* const* d_in, const int* in_sizes, int n_in,
                              void* d_out, int out_size, void* d_ws, size_t ws_size,
                              hipStream_t stream) {
  (void)in_sizes; (void)n_in; (void)out_size; (void)ws_size;
  const float* x      = (const float*)d_in[0];
  const float* w_qkv  = (const float*)d_in[1];
  const float* b_qkv  = (const float*)d_in[2];
  const float* w_proj = (const float*)d_in[3];
  const float* b_proj = (const float*)d_in[4];
  const float* rel    = (const float*)d_in[5];
  float* out = (float*)d_out;

  float* qkv  = (float*)d_ws;                                   // [B][1536][1024] f32: 25.2 MB
  float* aout = qkv + (size_t)BATCH * O_QKV * NPIX;             // [B][512][1024]  f32:  8.4 MB

  gemm_pix<<<dim3(NPIX / 64, O_QKV / 64, BATCH), 256, 0, stream>>>(x, w_qkv, b_qkv, qkv, O_QKV, CIN);
  attn_kernel<<<dim3(NPIX / 64, HEADS, BATCH), 256, 0, stream>>>(qkv, rel, aout);
  gemm_pix<<<dim3(NPIX / 64, DATTN / 64, BATCH), 256, 0, stream>>>(aout, w_proj, b_proj, out, DATTN, DATTN);
}

// Round 2
// 191.442 us; speedup vs baseline: 1.7219x; 1.7219x over previous
//
#include <hip/hip_runtime.h>
#include <cstdint>
#include <cstddef>

#define BATCH 4
#define CIN   512
#define NPIX  1024
#define HEADS 16
#define DH    32
#define DATTN 512
#define O_QKV 1536

typedef unsigned short u16;
typedef __bf16 bf16x8 __attribute__((ext_vector_type(8)));
typedef float  f32x4  __attribute__((ext_vector_type(4)));

__device__ __forceinline__ u16 f2bf(float f) {
  unsigned u = __float_as_uint(f);
  u += 0x7fffu + ((u >> 16) & 1u);
  return (u16)(u >> 16);
}

// ---------------------------------------------------------------------------
// QKV 1x1-conv GEMM: out[o][n] = sum_k w[o][k] x[b][k][n] + bias[o], K=512.
// Epilogue: bf16. q/k stored TRANSPOSED per head: qt/kt[b][h][n][32].
// v stored natural: vnat[b][o][n] (only rows with (o%96)>=64 are used).
// ---------------------------------------------------------------------------
__global__ __launch_bounds__(256) void gemm_qkv(const float* __restrict__ in,
                                                const float* __restrict__ w,
                                                const float* __restrict__ bias,
                                                u16* __restrict__ qt,
                                                u16* __restrict__ kt,
                                                u16* __restrict__ vnat) {
  __shared__ float sA[16][64];
  __shared__ float sB[16][64];
  const int t  = threadIdx.x;
  const int b  = blockIdx.z;
  const int o0 = blockIdx.y * 64;
  const int n0 = blockIdx.x * 64;
  const int tx = t & 15, ty = t >> 4;
  const float* inb = in + (size_t)b * CIN * NPIX;

  float acc[4][4] = {{0.f}};
  const int oA  = t >> 2;
  const int kkA = (t & 3) << 2;
  const int kkB = t >> 4;
  const int nB  = (t & 15) << 2;

  for (int k = 0; k < CIN; k += 16) {
    float4 a4 = *reinterpret_cast<const float4*>(&w[(size_t)(o0 + oA) * CIN + k + kkA]);
    sA[kkA + 0][oA] = a4.x; sA[kkA + 1][oA] = a4.y;
    sA[kkA + 2][oA] = a4.z; sA[kkA + 3][oA] = a4.w;
    *reinterpret_cast<float4*>(&sB[kkB][nB]) =
        *reinterpret_cast<const float4*>(&inb[(size_t)(k + kkB) * NPIX + n0 + nB]);
    __syncthreads();
#pragma unroll
    for (int kk = 0; kk < 16; ++kk) {
      float4 av = *reinterpret_cast<const float4*>(&sA[kk][ty << 2]);
      float4 bv = *reinterpret_cast<const float4*>(&sB[kk][tx << 2]);
      acc[0][0] += av.x * bv.x; acc[0][1] += av.x * bv.y; acc[0][2] += av.x * bv.z; acc[0][3] += av.x * bv.w;
      acc[1][0] += av.y * bv.x; acc[1][1] += av.y * bv.y; acc[1][2] += av.y * bv.z; acc[1][3] += av.y * bv.w;
      acc[2][0] += av.z * bv.x; acc[2][1] += av.z * bv.y; acc[2][2] += av.z * bv.z; acc[2][3] += av.z * bv.w;
      acc[3][0] += av.w * bv.x; acc[3][1] += av.w * bv.y; acc[3][2] += av.w * bv.z; acc[3][3] += av.w * bv.w;
    }
    __syncthreads();
  }

#pragma unroll
  for (int i = 0; i < 4; ++i) {
    const int o = o0 + (ty << 2) + i;
    const float bb = bias[o];
    float v0 = acc[i][0] + bb, v1 = acc[i][1] + bb, v2 = acc[i][2] + bb, v3 = acc[i][3] + bb;
    const int h = o / 96, r = o - h * 96;
    const int nbase = n0 + (tx << 2);
    if (r < 64) {
      u16* base = (r < 32) ? qt : kt;
      const int d = r & 31;
      const size_t rb = ((size_t)(b * HEADS + h)) * NPIX * DH + d;
      base[rb + (size_t)(nbase + 0) * DH] = f2bf(v0);
      base[rb + (size_t)(nbase + 1) * DH] = f2bf(v1);
      base[rb + (size_t)(nbase + 2) * DH] = f2bf(v2);
      base[rb + (size_t)(nbase + 3) * DH] = f2bf(v3);
    } else {
      unsigned lo = (unsigned)f2bf(v0) | ((unsigned)f2bf(v1) << 16);
      unsigned hi = (unsigned)f2bf(v2) | ((unsigned)f2bf(v3) << 16);
      *reinterpret_cast<uint2*>(&vnat[((size_t)b * O_QKV + o) * NPIX + nbase]) = make_uint2(lo, hi);
    }
  }
}

// ---------------------------------------------------------------------------
// MFMA flash attention. Block = (i-tile of 64, head); batch looped INSIDE so
// rel_pos is read once per block (held in regs, reused x4 batches).
// S = scale*(Q^T K) + rel ; P = exp(S) (scores bounded, no max needed);
// out[i][d] = sum_j P[i,j] V[d,j] / sum_j P[i,j].
// 4 waves; wave w owns i-rows [16w,16w+16). K/V double-buffered in LDS.
// ---------------------------------------------------------------------------
__global__ __launch_bounds__(256) void attn_mfma(const u16* __restrict__ qt,
                                                 const u16* __restrict__ kt,
                                                 const u16* __restrict__ qkvb,
                                                 const float* __restrict__ rel,
                                                 float* __restrict__ aout) {
  __shared__ __align__(16) u16 sK[2][64 * 32];   // [j][d] linear, 64B rows
  __shared__ __align__(16) u16 sV[2][32 * 72];   // [d][j] padded to 72
  __shared__ __align__(16) u16 sP[4][16 * 72];   // per-wave P transpose buffer

  const int t  = threadIdx.x;
  const int w  = t >> 6, l = t & 63, g = l >> 4, ln = l & 15;
  const int i0 = blockIdx.x * 64;
  const int h  = blockIdx.y;
  const float scale = 0.17677669529663687f;

  // Q fragments (A-operand): lane -> row i0+16w+ln, k = 8g..8g+7
  bf16x8 qf[BATCH];
#pragma unroll
  for (int b = 0; b < BATCH; ++b)
    qf[b] = *reinterpret_cast<const bf16x8*>(
        qt + (((size_t)(b * HEADS + h)) * NPIX + i0 + (w << 4) + ln) * DH + (g << 3));

  const int krow = t >> 2, kch = t & 3;   // K staging: row j=krow, 16B chunk kch
  const int vd = t & 31, vc = t >> 5;     // V staging: row d=vd, 16B chunk vc

  f32x4 vzero = {0.f, 0.f, 0.f, 0.f};
  f32x4 accO[BATCH][2];
  float l_run[BATCH][4];
#pragma unroll
  for (int b = 0; b < BATCH; ++b) {
    accO[b][0] = vzero; accO[b][1] = vzero;
#pragma unroll
    for (int v = 0; v < 4; ++v) l_run[b][v] = 0.f;
  }

  // rel fragment regs: element (jj,v) = rel[h][i0+16w+4g+v][j0+16jj+ln]
  const float* relp = rel + ((size_t)h * NPIX + i0 + (w << 4) + (g << 2)) * NPIX + ln;
  float relA[16], relB[16];
#pragma unroll
  for (int jj = 0; jj < 4; ++jj)
#pragma unroll
    for (int v = 0; v < 4; ++v)
      relA[(jj << 2) + v] = relp[(size_t)v * NPIX + (jj << 4)];

  const size_t ktbase = (size_t)h * NPIX * DH;
  // prologue: stage step (js=0, b=0) into buffer 0
  uint4 kreg = *reinterpret_cast<const uint4*>(kt + ktbase + (size_t)krow * DH + (kch << 3));
  uint4 vreg = *reinterpret_cast<const uint4*>(
      qkvb + ((size_t)(h * 96 + 64 + vd)) * NPIX + (vc << 3));
  *reinterpret_cast<uint4*>(&sK[0][(krow << 5) + (kch << 3)]) = kreg;
  *reinterpret_cast<uint4*>(&sV[0][vd * 72 + (vc << 3)]) = vreg;
  __syncthreads();

  u16* sPw = &sP[w][0];

  for (int js = 0; js < 16; ++js) {
#pragma unroll
    for (int b = 0; b < BATCH; ++b) {
      const int p = b & 1;                       // s = 4*js+b -> parity = b&1
      const int nb = (b + 1) & 3;
      const int njs = (b == 3) ? js + 1 : js;
      const bool do_next = (njs < 16);
      if (do_next) {                             // early-issue next step's loads
        kreg = *reinterpret_cast<const uint4*>(
            kt + (size_t)nb * (HEADS * NPIX * DH) + ktbase +
            ((size_t)(njs << 6) + krow) * DH + (kch << 3));
        vreg = *reinterpret_cast<const uint4*>(
            qkvb + ((size_t)nb * O_QKV + h * 96 + 64 + vd) * NPIX + (njs << 6) + (vc << 3));
      }
      if (b == 0 && js < 15) {                   // prefetch next j-step's rel
#pragma unroll
        for (int jj = 0; jj < 4; ++jj)
#pragma unroll
          for (int v = 0; v < 4; ++v)
            relB[(jj << 2) + v] = relp[(size_t)v * NPIX + ((js + 1) << 6) + (jj << 4)];
      }

      // ---- S = Q^T K (4 fragments of 16x16, K=32 in one MFMA) ----
      f32x4 sfr[4];
#pragma unroll
      for (int jj = 0; jj < 4; ++jj) {
        bf16x8 kf = *reinterpret_cast<const bf16x8*>(&sK[p][((jj << 4) + ln) * DH + (g << 3)]);
        sfr[jj] = __builtin_amdgcn_mfma_f32_16x16x32_bf16(qf[b], kf, vzero, 0, 0, 0);
      }

      // ---- softmax numerator (bounded scores: no max tracking) ----
#pragma unroll
      for (int v = 0; v < 4; ++v) {
        float p0 = __expf(sfr[0][v] * scale + relA[0 + v]);
        float p1 = __expf(sfr[1][v] * scale + relA[4 + v]);
        float p2 = __expf(sfr[2][v] * scale + relA[8 + v]);
        float p3 = __expf(sfr[3][v] * scale + relA[12 + v]);
        float ls = (p0 + p1) + (p2 + p3);
        ls += __shfl_xor(ls, 1);
        ls += __shfl_xor(ls, 2);
        ls += __shfl_xor(ls, 4);
        ls += __shfl_xor(ls, 8);
        l_run[b][v] += ls;
        const int prow = ((g << 2) + v) * 72 + ln;   // P[i][j] transpose via LDS
        sPw[prow +  0] = f2bf(p0);
        sPw[prow + 16] = f2bf(p1);
        sPw[prow + 32] = f2bf(p2);
        sPw[prow + 48] = f2bf(p3);
      }

      // ---- PV: acc[i][d] += P[i,j] * V[d,j], j in 2 chunks of 32 ----
#pragma unroll
      for (int kc = 0; kc < 2; ++kc) {
        bf16x8 pa = *reinterpret_cast<const bf16x8*>(&sPw[ln * 72 + (kc << 5) + (g << 3)]);
#pragma unroll
        for (int dc = 0; dc < 2; ++dc) {
          bf16x8 vf = *reinterpret_cast<const bf16x8*>(
              &sV[p][((dc << 4) + ln) * 72 + (kc << 5) + (g << 3)]);
          accO[b][dc] = __builtin_amdgcn_mfma_f32_16x16x32_bf16(pa, vf, accO[b][dc], 0, 0, 0);
        }
      }

      // ---- write next step's K/V into the other buffer ----
      if (do_next) {
        *reinterpret_cast<uint4*>(&sK[p ^ 1][(krow << 5) + (kch << 3)]) = kreg;
        *reinterpret_cast<uint4*>(&sV[p ^ 1][vd * 72 + (vc << 3)]) = vreg;
      }
      __syncthreads();
    }
    if (js < 15) {
#pragma unroll
      for (int e = 0; e < 16; ++e) relA[e] = relB[e];
    }
  }

  // ---- epilogue: divide by row sum, write transposed aout[b][n][c] ----
#pragma unroll
  for (int b = 0; b < BATCH; ++b)
#pragma unroll
    for (int v = 0; v < 4; ++v) {
      float inv = 1.f / l_run[b][v];
      size_t row = (size_t)b * NPIX + i0 + (w << 4) + (g << 2) + v;
#pragma unroll
      for (int dc = 0; dc < 2; ++dc)
        aout[row * DATTN + (h << 5) + (dc << 4) + ln] = accO[b][dc][v] * inv;
    }
}

// ---------------------------------------------------------------------------
// Proj GEMM: out[b][o][n] = sum_k w[o][k] * at[b][n][k] + bias[o]  (K=512)
// Input is the attention's transposed [n][c] layout; staged with transpose.
// ---------------------------------------------------------------------------
__global__ __launch_bounds__(256) void gemm_proj(const float* __restrict__ at,
                                                 const float* __restrict__ w,
                                                 const float* __restrict__ bias,
                                                 float* __restrict__ out) {
  __shared__ float sA[16][64];
  __shared__ float sB[16][68];
  const int t  = threadIdx.x;
  const int b  = blockIdx.z;
  const int o0 = blockIdx.y * 64;
  const int n0 = blockIdx.x * 64;
  const int tx = t & 15, ty = t >> 4;

  float acc[4][4] = {{0.f}};
  const int oA  = t >> 2;
  const int kkA = (t & 3) << 2;
  const int nB2 = t >> 2;          // 0..63
  const int kc2 = t & 3;           // 0..3

  for (int k = 0; k < DATTN; k += 16) {
    float4 a4 = *reinterpret_cast<const float4*>(&w[(size_t)(o0 + oA) * DATTN + k + kkA]);
    sA[kkA + 0][oA] = a4.x; sA[kkA + 1][oA] = a4.y;
    sA[kkA + 2][oA] = a4.z; sA[kkA + 3][oA] = a4.w;
    float4 b4 = *reinterpret_cast<const float4*>(
        &at[((size_t)b * NPIX + n0 + nB2) * DATTN + k + (kc2 << 2)]);
    sB[(kc2 << 2) + 0][nB2] = b4.x; sB[(kc2 << 2) + 1][nB2] = b4.y;
    sB[(kc2 << 2) + 2][nB2] = b4.z; sB[(kc2 << 2) + 3][nB2] = b4.w;
    __syncthreads();
#pragma unroll
    for (int kk = 0; kk < 16; ++kk) {
      float4 av = *reinterpret_cast<const float4*>(&sA[kk][ty << 2]);
      float4 bv = *reinterpret_cast<const float4*>(&sB[kk][tx << 2]);
      acc[0][0] += av.x * bv.x; acc[0][1] += av.x * bv.y; acc[0][2] += av.x * bv.z; acc[0][3] += av.x * bv.w;
      acc[1][0] += av.y * bv.x; acc[1][1] += av.y * bv.y; acc[1][2] += av.y * bv.z; acc[1][3] += av.y * bv.w;
      acc[2][0] += av.z * bv.x; acc[2][1] += av.z * bv.y; acc[2][2] += av.z * bv.z; acc[2][3] += av.z * bv.w;
      acc[3][0] += av.w * bv.x; acc[3][1] += av.w * bv.y; acc[3][2] += av.w * bv.z; acc[3][3] += av.w * bv.w;
    }
    __syncthreads();
  }

#pragma unroll
  for (int i = 0; i < 4; ++i) {
    const int o = o0 + (ty << 2) + i;
    const float bb = bias[o];
    float4 r = make_float4(acc[i][0] + bb, acc[i][1] + bb, acc[i][2] + bb, acc[i][3] + bb);
    *reinterpret_cast<float4*>(&out[((size_t)b * DATTN + o) * NPIX + n0 + (tx << 2)]) = r;
  }
}

extern "C" void kernel_launch(void* const* d_in, const int* in_sizes, int n_in,
                              void* d_out, int out_size, void* d_ws, size_t ws_size,
                              hipStream_t stream) {
  (void)in_sizes; (void)n_in; (void)out_size; (void)ws_size;
  const float* x      = (const float*)d_in[0];
  const float* w_qkv  = (const float*)d_in[1];
  const float* b_qkv  = (const float*)d_in[2];
  const float* w_proj = (const float*)d_in[3];
  const float* b_proj = (const float*)d_in[4];
  const float* rel    = (const float*)d_in[5];
  float* out = (float*)d_out;

  u16* qkvb = (u16*)d_ws;                                      // 12.58 MB (v rows)
  u16* qt   = qkvb + (size_t)BATCH * O_QKV * NPIX;             // 4 MB
  u16* kt   = qt + (size_t)BATCH * HEADS * NPIX * DH;          // 4 MB
  float* aout = (float*)(kt + (size_t)BATCH * HEADS * NPIX * DH);  // 8.4 MB

  gemm_qkv<<<dim3(NPIX / 64, O_QKV / 64, BATCH), 256, 0, stream>>>(x, w_qkv, b_qkv, qt, kt, qkvb);
  attn_mfma<<<dim3(NPIX / 64, HEADS), 256, 0, stream>>>(qt, kt, qkvb, rel, aout);
  gemm_proj<<<dim3(NPIX / 64, DATTN / 64, BATCH), 256, 0, stream>>>(aout, w_proj, b_proj, out);
}

// Round 3
// 94.193 us; speedup vs baseline: 3.4997x; 2.0324x over previous
//
#include <hip/hip_runtime.h>
#include <cstdint>
#include <cstddef>

#define BATCH 4
#define CIN   512
#define NPIX  1024
#define HEADS 16
#define DH    32
#define DATTN 512
#define O_QKV 1536

typedef unsigned short u16;
typedef __bf16 bf16x8 __attribute__((ext_vector_type(8)));
typedef float  f32x4  __attribute__((ext_vector_type(4)));

typedef const __attribute__((address_space(1))) void g1_t;
typedef __attribute__((address_space(3))) void l3_t;

__device__ __forceinline__ u16 f2bf(float f) {
  unsigned u = __float_as_uint(f);
  u += 0x7fffu + ((u >> 16) & 1u);
  return (u16)(u >> 16);
}

// async global->LDS, 16B per lane; lp must be wave-uniform (HW: base + lane*16)
__device__ __forceinline__ void gl_lds16(const void* gp, void* lp) {
  __builtin_amdgcn_global_load_lds((g1_t*)gp, (l3_t*)lp, 16, 0, 0);
}

// ---------------------------------------------------------------------------
// prep_w: convert w_qkv [1536][512] and w_proj [512][512] f32 -> bf16.
// ---------------------------------------------------------------------------
__global__ __launch_bounds__(256) void prep_w(const float* __restrict__ w1,
                                              const float* __restrict__ w2,
                                              u16* __restrict__ o1,
                                              u16* __restrict__ o2) {
  const int idx = blockIdx.x * 256 + threadIdx.x;   // float4 index
  const int n1 = (O_QKV * CIN) >> 2;                // 196608
  float4 v = (idx < n1) ? reinterpret_cast<const float4*>(w1)[idx]
                        : reinterpret_cast<const float4*>(w2)[idx - n1];
  uint2 pk = make_uint2((unsigned)f2bf(v.x) | ((unsigned)f2bf(v.y) << 16),
                        (unsigned)f2bf(v.z) | ((unsigned)f2bf(v.w) << 16));
  if (idx < n1) reinterpret_cast<uint2*>(o1)[idx] = pk;
  else          reinterpret_cast<uint2*>(o2)[idx - n1] = pk;
}

// ---------------------------------------------------------------------------
// prep_x: x [B][C][N] f32 -> xt [B][N][C] bf16 (tiled 64x64 LDS transpose)
// ---------------------------------------------------------------------------
__global__ __launch_bounds__(256) void prep_x(const float* __restrict__ x,
                                              u16* __restrict__ xt) {
  __shared__ float sT[64][65];
  const int t  = threadIdx.x;
  const int n0 = blockIdx.x * 64;
  const int c0 = blockIdx.y * 64;
  const int b  = blockIdx.z;
  const float* xb = x + ((size_t)b * CIN + c0) * NPIX + n0;
#pragma unroll
  for (int i = 0; i < 4; ++i) {
    int r   = i * 16 + (t >> 4);
    int col = (t & 15) << 2;
    float4 v = *reinterpret_cast<const float4*>(&xb[(size_t)r * NPIX + col]);
    sT[r][col + 0] = v.x; sT[r][col + 1] = v.y;
    sT[r][col + 2] = v.z; sT[r][col + 3] = v.w;
  }
  __syncthreads();
#pragma unroll
  for (int i = 0; i < 2; ++i) {
    int nl = t >> 2;
    int ch = (t & 3) + (i << 2);
    u16 tmp[8];
#pragma unroll
    for (int e = 0; e < 8; ++e) tmp[e] = f2bf(sT[(ch << 3) + e][nl]);
    *reinterpret_cast<uint4*>(&xt[((size_t)b * NPIX + n0 + nl) * CIN + c0 + (ch << 3)]) =
        *reinterpret_cast<uint4*>(tmp);
  }
}

// ---------------------------------------------------------------------------
// QKV GEMM (MFMA): C[o][n] = sum_k Wq[o,k] * XT[n,k], per (head, n-tile, b).
// M-tile = 96 (one head: q rows 0-31, k 32-63, v 64-95), N-tile 128, BK=64.
// 4 waves (2m x 2n), wave tile 48x64 = 3x4 frags of 16x16x32.
// Epilogue: +bias, bf16, write qt/kt [b][h][n][32] and vt [b][h][d][n].
// ---------------------------------------------------------------------------
__global__ __launch_bounds__(256) void gemm_qkv_mfma(const u16* __restrict__ wq,
                                                     const u16* __restrict__ xt,
                                                     const float* __restrict__ bias,
                                                     u16* __restrict__ qt,
                                                     u16* __restrict__ kt,
                                                     u16* __restrict__ vt) {
  __shared__ __align__(16) u16 sA[96 * 64];
  __shared__ __align__(16) u16 sB[128 * 64];
  const int t  = threadIdx.x;
  const int w  = t >> 6, l = t & 63, g = l >> 4, ln = l & 15;
  const int n0 = blockIdx.x * 128;
  const int h  = blockIdx.y;
  const int b  = blockIdx.z;
  const int wm = w >> 1, wn = w & 1;

  const u16* wbase = wq + (size_t)h * 96 * CIN;
  const u16* xbase = xt + ((size_t)b * NPIX + n0) * CIN;

  f32x4 acc[3][4];
#pragma unroll
  for (int mi = 0; mi < 3; ++mi)
#pragma unroll
    for (int ni = 0; ni < 4; ++ni) acc[mi][ni] = {0.f, 0.f, 0.f, 0.f};

  for (int k0 = 0; k0 < CIN; k0 += 64) {
    // stage A: 96x64 bf16 = 768 chunks (3/wave-lane)
#pragma unroll
    for (int i = 0; i < 3; ++i) {
      int chunk = i * 256 + (w << 6) + l;
      gl_lds16(wbase + ((size_t)(chunk >> 3)) * CIN + k0 + ((chunk & 7) << 3),
               (char*)sA + i * 4096 + (w << 10));
    }
    // stage B: 128x64 bf16 = 1024 chunks (4/wave-lane)
#pragma unroll
    for (int i = 0; i < 4; ++i) {
      int chunk = i * 256 + (w << 6) + l;
      gl_lds16(xbase + ((size_t)(chunk >> 3)) * CIN + k0 + ((chunk & 7) << 3),
               (char*)sB + i * 4096 + (w << 10));
    }
    __syncthreads();
#pragma unroll
    for (int kk = 0; kk < 64; kk += 32) {
      bf16x8 af[3], bfr[4];
#pragma unroll
      for (int mi = 0; mi < 3; ++mi)
        af[mi] = *reinterpret_cast<const bf16x8*>(&sA[(48 * wm + 16 * mi + ln) * 64 + kk + (g << 3)]);
#pragma unroll
      for (int ni = 0; ni < 4; ++ni)
        bfr[ni] = *reinterpret_cast<const bf16x8*>(&sB[((wn << 6) + (ni << 4) + ln) * 64 + kk + (g << 3)]);
#pragma unroll
      for (int mi = 0; mi < 3; ++mi)
#pragma unroll
        for (int ni = 0; ni < 4; ++ni)
          acc[mi][ni] = __builtin_amdgcn_mfma_f32_16x16x32_bf16(af[mi], bfr[ni], acc[mi][ni], 0, 0, 0);
    }
    __syncthreads();
  }

  const float* bh = bias + h * 96;
#pragma unroll
  for (int mi = 0; mi < 3; ++mi) {
    const int sec = 48 * wm + 16 * mi;              // 0,16,32,48,64,80
    const int rb  = sec + (g << 2);
    const float b0 = bh[rb + 0], b1 = bh[rb + 1], b2 = bh[rb + 2], b3 = bh[rb + 3];
#pragma unroll
    for (int ni = 0; ni < 4; ++ni) {
      const int n = n0 + (wn << 6) + (ni << 4) + ln;
      f32x4 a = acc[mi][ni];
      u16 e0 = f2bf(a[0] + b0), e1 = f2bf(a[1] + b1);
      u16 e2 = f2bf(a[2] + b2), e3 = f2bf(a[3] + b3);
      if (sec < 32) {
        const int d = sec + (g << 2);
        uint2 pk = make_uint2((unsigned)e0 | ((unsigned)e1 << 16),
                              (unsigned)e2 | ((unsigned)e3 << 16));
        *reinterpret_cast<uint2*>(&qt[(((size_t)(b * HEADS + h)) * NPIX + n) * DH + d]) = pk;
      } else if (sec < 64) {
        const int d = sec - 32 + (g << 2);
        uint2 pk = make_uint2((unsigned)e0 | ((unsigned)e1 << 16),
                              (unsigned)e2 | ((unsigned)e3 << 16));
        *reinterpret_cast<uint2*>(&kt[(((size_t)(b * HEADS + h)) * NPIX + n) * DH + d]) = pk;
      } else {
        const int d = sec - 64 + (g << 2);
        u16* vp = &vt[(((size_t)(b * HEADS + h)) * DH + d) * NPIX + n];
        vp[0] = e0; vp[NPIX] = e1; vp[2 * NPIX] = e2; vp[3 * NPIX] = e3;
      }
    }
  }
}

// ---------------------------------------------------------------------------
// MFMA flash attention (round-2 structure). V now in vt [b][h][d][n];
// output bf16 transposed aout [b][n][c].
// ---------------------------------------------------------------------------
__global__ __launch_bounds__(256) void attn_mfma(const u16* __restrict__ qt,
                                                 const u16* __restrict__ kt,
                                                 const u16* __restrict__ vt,
                                                 const float* __restrict__ rel,
                                                 u16* __restrict__ aout) {
  __shared__ __align__(16) u16 sK[2][64 * 32];
  __shared__ __align__(16) u16 sV[2][32 * 72];
  __shared__ __align__(16) u16 sP[4][16 * 72];

  const int t  = threadIdx.x;
  const int w  = t >> 6, l = t & 63, g = l >> 4, ln = l & 15;
  const int i0 = blockIdx.x * 64;
  const int h  = blockIdx.y;
  const float scale = 0.17677669529663687f;

  bf16x8 qf[BATCH];
#pragma unroll
  for (int b = 0; b < BATCH; ++b)
    qf[b] = *reinterpret_cast<const bf16x8*>(
        qt + (((size_t)(b * HEADS + h)) * NPIX + i0 + (w << 4) + ln) * DH + (g << 3));

  const int krow = t >> 2, kch = t & 3;
  const int vd = t & 31, vc = t >> 5;

  f32x4 vzero = {0.f, 0.f, 0.f, 0.f};
  f32x4 accO[BATCH][2];
  float l_run[BATCH][4];
#pragma unroll
  for (int b = 0; b < BATCH; ++b) {
    accO[b][0] = vzero; accO[b][1] = vzero;
#pragma unroll
    for (int v = 0; v < 4; ++v) l_run[b][v] = 0.f;
  }

  const float* relp = rel + ((size_t)h * NPIX + i0 + (w << 4) + (g << 2)) * NPIX + ln;
  float relA[16], relB[16];
#pragma unroll
  for (int jj = 0; jj < 4; ++jj)
#pragma unroll
    for (int v = 0; v < 4; ++v)
      relA[(jj << 2) + v] = relp[(size_t)v * NPIX + (jj << 4)];

  const size_t ktbase = (size_t)h * NPIX * DH;
  uint4 kreg = *reinterpret_cast<const uint4*>(kt + ktbase + (size_t)krow * DH + (kch << 3));
  uint4 vreg = *reinterpret_cast<const uint4*>(vt + ((size_t)h * DH + vd) * NPIX + (vc << 3));
  *reinterpret_cast<uint4*>(&sK[0][(krow << 5) + (kch << 3)]) = kreg;
  *reinterpret_cast<uint4*>(&sV[0][vd * 72 + (vc << 3)]) = vreg;
  __syncthreads();

  u16* sPw = &sP[w][0];

  for (int js = 0; js < 16; ++js) {
#pragma unroll
    for (int b = 0; b < BATCH; ++b) {
      const int p = b & 1;
      const int nb = (b + 1) & 3;
      const int njs = (b == 3) ? js + 1 : js;
      const bool do_next = (njs < 16);
      if (do_next) {
        kreg = *reinterpret_cast<const uint4*>(
            kt + (size_t)nb * (HEADS * NPIX * DH) + ktbase +
            ((size_t)(njs << 6) + krow) * DH + (kch << 3));
        vreg = *reinterpret_cast<const uint4*>(
            vt + ((size_t)((nb * HEADS + h) * DH) + vd) * NPIX + (njs << 6) + (vc << 3));
      }
      if (b == 0 && js < 15) {
#pragma unroll
        for (int jj = 0; jj < 4; ++jj)
#pragma unroll
          for (int v = 0; v < 4; ++v)
            relB[(jj << 2) + v] = relp[(size_t)v * NPIX + ((js + 1) << 6) + (jj << 4)];
      }

      f32x4 sfr[4];
#pragma unroll
      for (int jj = 0; jj < 4; ++jj) {
        bf16x8 kf = *reinterpret_cast<const bf16x8*>(&sK[p][((jj << 4) + ln) * DH + (g << 3)]);
        sfr[jj] = __builtin_amdgcn_mfma_f32_16x16x32_bf16(qf[b], kf, vzero, 0, 0, 0);
      }

#pragma unroll
      for (int v = 0; v < 4; ++v) {
        float p0 = __expf(sfr[0][v] * scale + relA[0 + v]);
        float p1 = __expf(sfr[1][v] * scale + relA[4 + v]);
        float p2 = __expf(sfr[2][v] * scale + relA[8 + v]);
        float p3 = __expf(sfr[3][v] * scale + relA[12 + v]);
        float ls = (p0 + p1) + (p2 + p3);
        ls += __shfl_xor(ls, 1);
        ls += __shfl_xor(ls, 2);
        ls += __shfl_xor(ls, 4);
        ls += __shfl_xor(ls, 8);
        l_run[b][v] += ls;
        const int prow = ((g << 2) + v) * 72 + ln;
        sPw[prow +  0] = f2bf(p0);
        sPw[prow + 16] = f2bf(p1);
        sPw[prow + 32] = f2bf(p2);
        sPw[prow + 48] = f2bf(p3);
      }

#pragma unroll
      for (int kc = 0; kc < 2; ++kc) {
        bf16x8 pa = *reinterpret_cast<const bf16x8*>(&sPw[ln * 72 + (kc << 5) + (g << 3)]);
#pragma unroll
        for (int dc = 0; dc < 2; ++dc) {
          bf16x8 vf = *reinterpret_cast<const bf16x8*>(
              &sV[p][((dc << 4) + ln) * 72 + (kc << 5) + (g << 3)]);
          accO[b][dc] = __builtin_amdgcn_mfma_f32_16x16x32_bf16(pa, vf, accO[b][dc], 0, 0, 0);
        }
      }

      if (do_next) {
        *reinterpret_cast<uint4*>(&sK[p ^ 1][(krow << 5) + (kch << 3)]) = kreg;
        *reinterpret_cast<uint4*>(&sV[p ^ 1][vd * 72 + (vc << 3)]) = vreg;
      }
      __syncthreads();
    }
    if (js < 15) {
#pragma unroll
      for (int e = 0; e < 16; ++e) relA[e] = relB[e];
    }
  }

#pragma unroll
  for (int b = 0; b < BATCH; ++b)
#pragma unroll
    for (int v = 0; v < 4; ++v) {
      float inv = 1.f / l_run[b][v];
      size_t row = (size_t)b * NPIX + i0 + (w << 4) + (g << 2) + v;
#pragma unroll
      for (int dc = 0; dc < 2; ++dc)
        aout[row * DATTN + (h << 5) + (dc << 4) + ln] = f2bf(accO[b][dc][v] * inv);
    }
}

// ---------------------------------------------------------------------------
// Proj GEMM (MFMA): out[b][o][n] = sum_k Wp[o,k] * A[b][n][k] + bias[o], f32 out.
// Tile 64(o) x 128(n), BK=64; 4 waves (2m x 2n), wave tile 32x64 = 2x4 frags.
// ---------------------------------------------------------------------------
__global__ __launch_bounds__(256) void gemm_proj_mfma(const u16* __restrict__ wp,
                                                      const u16* __restrict__ at,
                                                      const float* __restrict__ bias,
                                                      float* __restrict__ out) {
  __shared__ __align__(16) u16 sA[64 * 64];
  __shared__ __align__(16) u16 sB[128 * 64];
  const int t  = threadIdx.x;
  const int w  = t >> 6, l = t & 63, g = l >> 4, ln = l & 15;
  const int n0 = blockIdx.x * 128;
  const int o0 = blockIdx.y * 64;
  const int b  = blockIdx.z;
  const int wm = w >> 1, wn = w & 1;

  const u16* wbase = wp + (size_t)o0 * DATTN;
  const u16* abase = at + ((size_t)b * NPIX + n0) * DATTN;

  f32x4 acc[2][4];
#pragma unroll
  for (int mi = 0; mi < 2; ++mi)
#pragma unroll
    for (int ni = 0; ni < 4; ++ni) acc[mi][ni] = {0.f, 0.f, 0.f, 0.f};

  for (int k0 = 0; k0 < DATTN; k0 += 64) {
#pragma unroll
    for (int i = 0; i < 2; ++i) {
      int chunk = i * 256 + (w << 6) + l;
      gl_lds16(wbase + ((size_t)(chunk >> 3)) * DATTN + k0 + ((chunk & 7) << 3),
               (char*)sA + i * 4096 + (w << 10));
    }
#pragma unroll
    for (int i = 0; i < 4; ++i) {
      int chunk = i * 256 + (w << 6) + l;
      gl_lds16(abase + ((size_t)(chunk >> 3)) * DATTN + k0 + ((chunk & 7) << 3),
               (char*)sB + i * 4096 + (w << 10));
    }
    __syncthreads();
#pragma unroll
    for (int kk = 0; kk < 64; kk += 32) {
      bf16x8 af[2], bfr[4];
#pragma unroll
      for (int mi = 0; mi < 2; ++mi)
        af[mi] = *reinterpret_cast<const bf16x8*>(&sA[((wm << 5) + (mi << 4) + ln) * 64 + kk + (g << 3)]);
#pragma unroll
      for (int ni = 0; ni < 4; ++ni)
        bfr[ni] = *reinterpret_cast<const bf16x8*>(&sB[((wn << 6) + (ni << 4) + ln) * 64 + kk + (g << 3)]);
#pragma unroll
      for (int mi = 0; mi < 2; ++mi)
#pragma unroll
        for (int ni = 0; ni < 4; ++ni)
          acc[mi][ni] = __builtin_amdgcn_mfma_f32_16x16x32_bf16(af[mi], bfr[ni], acc[mi][ni], 0, 0, 0);
    }
    __syncthreads();
  }

#pragma unroll
  for (int mi = 0; mi < 2; ++mi) {
    const int o = o0 + (wm << 5) + (mi << 4) + (g << 2);
    const float b0 = bias[o], b1 = bias[o + 1], b2 = bias[o + 2], b3 = bias[o + 3];
#pragma unroll
    for (int ni = 0; ni < 4; ++ni) {
      const int n = n0 + (wn << 6) + (ni << 4) + ln;
      float* op = &out[((size_t)b * DATTN + o) * NPIX + n];
      op[0]        = acc[mi][ni][0] + b0;
      op[NPIX]     = acc[mi][ni][1] + b1;
      op[2 * NPIX] = acc[mi][ni][2] + b2;
      op[3 * NPIX] = acc[mi][ni][3] + b3;
    }
  }
}

extern "C" void kernel_launch(void* const* d_in, const int* in_sizes, int n_in,
                              void* d_out, int out_size, void* d_ws, size_t ws_size,
                              hipStream_t stream) {
  (void)in_sizes; (void)n_in; (void)out_size; (void)ws_size;
  const float* x      = (const float*)d_in[0];
  const float* w_qkv  = (const float*)d_in[1];
  const float* b_qkv  = (const float*)d_in[2];
  const float* w_proj = (const float*)d_in[3];
  const float* b_proj = (const float*)d_in[4];
  const float* rel    = (const float*)d_in[5];
  float* out = (float*)d_out;

  u16* xt    = (u16*)d_ws;                                   // 2M elems, 4 MB
  u16* wq_bf = xt + (size_t)BATCH * NPIX * CIN;              // 786432, 1.5 MB
  u16* wp_bf = wq_bf + (size_t)O_QKV * CIN;                  // 262144, 0.5 MB
  u16* qt    = wp_bf + (size_t)DATTN * DATTN;                // 2M, 4 MB
  u16* kt    = qt + (size_t)BATCH * HEADS * NPIX * DH;       // 2M, 4 MB
  u16* vt    = kt + (size_t)BATCH * HEADS * NPIX * DH;       // 2M, 4 MB
  u16* aout  = vt + (size_t)BATCH * HEADS * NPIX * DH;       // 2M, 4 MB

  prep_w<<<1024, 256, 0, stream>>>(w_qkv, w_proj, wq_bf, wp_bf);
  prep_x<<<dim3(NPIX / 64, CIN / 64, BATCH), 256, 0, stream>>>(x, xt);
  gemm_qkv_mfma<<<dim3(NPIX / 128, HEADS, BATCH), 256, 0, stream>>>(wq_bf, xt, b_qkv, qt, kt, vt);
  attn_mfma<<<dim3(NPIX / 64, HEADS), 256, 0, stream>>>(qt, kt, vt, rel, aout);
  gemm_proj_mfma<<<dim3(NPIX / 128, DATTN / 64, BATCH), 256, 0, stream>>>(wp_bf, aout, b_proj, out);
}

// Round 4
// 70.983 us; speedup vs baseline: 4.6440x; 1.3270x over previous
//
#include <hip/hip_runtime.h>
#include <cstdint>
#include <cstddef>

#define BATCH 4
#define CIN   512
#define NPIX  1024
#define HEADS 16
#define DH    32
#define DATTN 512
#define O_QKV 1536

typedef unsigned short u16;
typedef __bf16 bf16x8 __attribute__((ext_vector_type(8)));
typedef float  f32x4  __attribute__((ext_vector_type(4)));

typedef const __attribute__((address_space(1))) void g1_t;
typedef __attribute__((address_space(3))) void l3_t;

__device__ __forceinline__ u16 f2bf(float f) {
  unsigned u = __float_as_uint(f);
  u += 0x7fffu + ((u >> 16) & 1u);
  return (u16)(u >> 16);
}

// async global->LDS, 16B per lane; lp must be wave-uniform (HW: base + lane*16)
__device__ __forceinline__ void gl_lds16(const void* gp, void* lp) {
  __builtin_amdgcn_global_load_lds((g1_t*)gp, (l3_t*)lp, 16, 0, 0);
}

// ---------------------------------------------------------------------------
// prep_w: convert w_qkv [1536][512] and w_proj [512][512] f32 -> bf16.
// ---------------------------------------------------------------------------
__global__ __launch_bounds__(256) void prep_w(const float* __restrict__ w1,
                                              const float* __restrict__ w2,
                                              u16* __restrict__ o1,
                                              u16* __restrict__ o2) {
  const int idx = blockIdx.x * 256 + threadIdx.x;   // float4 index
  const int n1 = (O_QKV * CIN) >> 2;                // 196608
  float4 v = (idx < n1) ? reinterpret_cast<const float4*>(w1)[idx]
                        : reinterpret_cast<const float4*>(w2)[idx - n1];
  uint2 pk = make_uint2((unsigned)f2bf(v.x) | ((unsigned)f2bf(v.y) << 16),
                        (unsigned)f2bf(v.z) | ((unsigned)f2bf(v.w) << 16));
  if (idx < n1) reinterpret_cast<uint2*>(o1)[idx] = pk;
  else          reinterpret_cast<uint2*>(o2)[idx - n1] = pk;
}

// ---------------------------------------------------------------------------
// prep_x: x [B][C][N] f32 -> xt [B][N][C] bf16 (tiled 64x64 LDS transpose)
// ---------------------------------------------------------------------------
__global__ __launch_bounds__(256) void prep_x(const float* __restrict__ x,
                                              u16* __restrict__ xt) {
  __shared__ float sT[64][65];
  const int t  = threadIdx.x;
  const int n0 = blockIdx.x * 64;
  const int c0 = blockIdx.y * 64;
  const int b  = blockIdx.z;
  const float* xb = x + ((size_t)b * CIN + c0) * NPIX + n0;
#pragma unroll
  for (int i = 0; i < 4; ++i) {
    int r   = i * 16 + (t >> 4);
    int col = (t & 15) << 2;
    float4 v = *reinterpret_cast<const float4*>(&xb[(size_t)r * NPIX + col]);
    sT[r][col + 0] = v.x; sT[r][col + 1] = v.y;
    sT[r][col + 2] = v.z; sT[r][col + 3] = v.w;
  }
  __syncthreads();
#pragma unroll
  for (int i = 0; i < 2; ++i) {
    int nl = t >> 2;
    int ch = (t & 3) + (i << 2);
    u16 tmp[8];
#pragma unroll
    for (int e = 0; e < 8; ++e) tmp[e] = f2bf(sT[(ch << 3) + e][nl]);
    *reinterpret_cast<uint4*>(&xt[((size_t)b * NPIX + n0 + nl) * CIN + c0 + (ch << 3)]) =
        *reinterpret_cast<uint4*>(tmp);
  }
}

// ---------------------------------------------------------------------------
// QKV GEMM (MFMA): M-tile=96 (one head), N-tile=128, BK=64, 4 waves.
// Epilogue: +bias, bf16; qt/kt [b][h][n][32], vt [b][h][d][n].
// ---------------------------------------------------------------------------
__global__ __launch_bounds__(256) void gemm_qkv_mfma(const u16* __restrict__ wq,
                                                     const u16* __restrict__ xt,
                                                     const float* __restrict__ bias,
                                                     u16* __restrict__ qt,
                                                     u16* __restrict__ kt,
                                                     u16* __restrict__ vt) {
  __shared__ __align__(16) u16 sA[96 * 64];
  __shared__ __align__(16) u16 sB[128 * 64];
  const int t  = threadIdx.x;
  const int w  = t >> 6, l = t & 63, g = l >> 4, ln = l & 15;
  const int n0 = blockIdx.x * 128;
  const int h  = blockIdx.y;
  const int b  = blockIdx.z;
  const int wm = w >> 1, wn = w & 1;

  const u16* wbase = wq + (size_t)h * 96 * CIN;
  const u16* xbase = xt + ((size_t)b * NPIX + n0) * CIN;

  f32x4 acc[3][4];
#pragma unroll
  for (int mi = 0; mi < 3; ++mi)
#pragma unroll
    for (int ni = 0; ni < 4; ++ni) acc[mi][ni] = {0.f, 0.f, 0.f, 0.f};

  for (int k0 = 0; k0 < CIN; k0 += 64) {
#pragma unroll
    for (int i = 0; i < 3; ++i) {
      int chunk = i * 256 + (w << 6) + l;
      gl_lds16(wbase + ((size_t)(chunk >> 3)) * CIN + k0 + ((chunk & 7) << 3),
               (char*)sA + i * 4096 + (w << 10));
    }
#pragma unroll
    for (int i = 0; i < 4; ++i) {
      int chunk = i * 256 + (w << 6) + l;
      gl_lds16(xbase + ((size_t)(chunk >> 3)) * CIN + k0 + ((chunk & 7) << 3),
               (char*)sB + i * 4096 + (w << 10));
    }
    __syncthreads();
#pragma unroll
    for (int kk = 0; kk < 64; kk += 32) {
      bf16x8 af[3], bfr[4];
#pragma unroll
      for (int mi = 0; mi < 3; ++mi)
        af[mi] = *reinterpret_cast<const bf16x8*>(&sA[(48 * wm + 16 * mi + ln) * 64 + kk + (g << 3)]);
#pragma unroll
      for (int ni = 0; ni < 4; ++ni)
        bfr[ni] = *reinterpret_cast<const bf16x8*>(&sB[((wn << 6) + (ni << 4) + ln) * 64 + kk + (g << 3)]);
#pragma unroll
      for (int mi = 0; mi < 3; ++mi)
#pragma unroll
        for (int ni = 0; ni < 4; ++ni)
          acc[mi][ni] = __builtin_amdgcn_mfma_f32_16x16x32_bf16(af[mi], bfr[ni], acc[mi][ni], 0, 0, 0);
    }
    __syncthreads();
  }

  const float* bh = bias + h * 96;
#pragma unroll
  for (int mi = 0; mi < 3; ++mi) {
    const int sec = 48 * wm + 16 * mi;
    const int rb  = sec + (g << 2);
    const float b0 = bh[rb + 0], b1 = bh[rb + 1], b2 = bh[rb + 2], b3 = bh[rb + 3];
#pragma unroll
    for (int ni = 0; ni < 4; ++ni) {
      const int n = n0 + (wn << 6) + (ni << 4) + ln;
      f32x4 a = acc[mi][ni];
      u16 e0 = f2bf(a[0] + b0), e1 = f2bf(a[1] + b1);
      u16 e2 = f2bf(a[2] + b2), e3 = f2bf(a[3] + b3);
      if (sec < 32) {
        const int d = sec + (g << 2);
        uint2 pk = make_uint2((unsigned)e0 | ((unsigned)e1 << 16),
                              (unsigned)e2 | ((unsigned)e3 << 16));
        *reinterpret_cast<uint2*>(&qt[(((size_t)(b * HEADS + h)) * NPIX + n) * DH + d]) = pk;
      } else if (sec < 64) {
        const int d = sec - 32 + (g << 2);
        uint2 pk = make_uint2((unsigned)e0 | ((unsigned)e1 << 16),
                              (unsigned)e2 | ((unsigned)e3 << 16));
        *reinterpret_cast<uint2*>(&kt[(((size_t)(b * HEADS + h)) * NPIX + n) * DH + d]) = pk;
      } else {
        const int d = sec - 64 + (g << 2);
        u16* vp = &vt[(((size_t)(b * HEADS + h)) * DH + d) * NPIX + n];
        vp[0] = e0; vp[NPIX] = e1; vp[2 * NPIX] = e2; vp[3 * NPIX] = e3;
      }
    }
  }
}

// ---------------------------------------------------------------------------
// MFMA flash attention, 8 waves (2 batches x 4 i-segs), 1 barrier per j-step.
// K LDS: per batch [32 packed rows r=j>>1][8 slots of 16B], slot ^= (r&7).
//   logical chunk cl: j = 2r + (cl>>2), d-chunk = cl&3.
// V LDS: per batch [32 d][8 slots of 16B], slot ^= (d&7); cl = n-chunk.
// Staged via global_load_lds with PRE-SWIZZLED global source (LDS linear).
// ---------------------------------------------------------------------------
__global__ __launch_bounds__(512, 4) void attn_mfma(const u16* __restrict__ qt,
                                                    const u16* __restrict__ kt,
                                                    const u16* __restrict__ vt,
                                                    const float* __restrict__ rel,
                                                    u16* __restrict__ aout) {
  __shared__ __align__(16) u16 sK[2][2 * 2048];   // [buf][2 local batches][32r][8slot][8]
  __shared__ __align__(16) u16 sV[2][2 * 2048];
  __shared__ __align__(16) u16 sP[8][16 * 72];

  const int t  = threadIdx.x;
  const int w  = t >> 6, l = t & 63, g = l >> 4, ln = l & 15;
  // XCD-aware decode: both bp-halves + 2 heads per XCD for L2 reuse
  const int bid = blockIdx.x;
  const int xcd = bid & 7, sl = bid >> 3;          // sl 0..63
  const int h   = (xcd << 1) | (sl >> 5);
  const int i0  = ((sl >> 1) & 15) << 6;
  const int bp  = sl & 1;                           // batch pair
  const int bw  = (bp << 1) | (w >> 2);             // this wave's batch
  const int iw  = w & 3;                            // i-segment
  const float scale = 0.17677669529663687f;

  // Q fragment: lane -> row i0+16*iw+ln, k = 8g..8g+7
  bf16x8 qf = *reinterpret_cast<const bf16x8*>(
      qt + (((size_t)(bw * HEADS + h)) * NPIX + i0 + (iw << 4) + ln) * DH + (g << 3));

  f32x4 vzero = {0.f, 0.f, 0.f, 0.f};
  f32x4 accO[2] = {vzero, vzero};
  float l_lane[4] = {0.f, 0.f, 0.f, 0.f};

  // staging mapping (constant per thread): chunk c = t (512 chunks per buffer half)
  {
    // nothing here; computed below
  }
  const int sc_b  = (bp << 1) | (t >> 8);           // global batch for staging
  const int sc_cb = t & 255;
  const int sc_r  = sc_cb >> 3;
  const int sc_cl = (sc_cb & 7) ^ (sc_r & 7);
  const u16* ksrc0 = kt + (((size_t)(sc_b * HEADS + h)) * NPIX +
                           ((sc_r << 1) | (sc_cl >> 2))) * DH + ((sc_cl & 3) << 3);
  const u16* vsrc0 = vt + (((size_t)(sc_b * HEADS + h)) * DH + sc_r) * NPIX + (sc_cl << 3);

#define STAGE(js_, p_) do {                                               \
    gl_lds16(ksrc0 + (size_t)(js_) * 2048, (char*)&sK[p_][0] + (w << 10)); \
    gl_lds16(vsrc0 + (size_t)(js_) * 64,   (char*)&sV[p_][0] + (w << 10)); \
  } while (0)

  // rel fragment regs: element (jj,v) = rel[h][i0+16*iw+4g+v][js*64+16*jj+ln]
  const float* relp = rel + ((size_t)h * NPIX + i0 + (iw << 4) + (g << 2)) * NPIX + ln;
  float relA[16], relB[16];
#pragma unroll
  for (int jj = 0; jj < 4; ++jj)
#pragma unroll
    for (int v = 0; v < 4; ++v)
      relA[(jj << 2) + v] = relp[(size_t)v * NPIX + (jj << 4)];

  STAGE(0, 0);

  u16* sPw = &sP[w][0];
  const int lb = w >> 2;                            // local batch index (0/1)

  for (int js = 0; js < 16; ++js) {
    const int p = js & 1;
    __syncthreads();                                // buf p ready; buf p^1 free
    if (js < 15) {
      STAGE(js + 1, p ^ 1);
#pragma unroll
      for (int jj = 0; jj < 4; ++jj)
#pragma unroll
        for (int v = 0; v < 4; ++v)
          relB[(jj << 2) + v] = relp[(size_t)v * NPIX + ((js + 1) << 6) + (jj << 4)];
    }

    const u16* Kb = &sK[p][lb << 11];
    const u16* Vb = &sV[p][lb << 11];

    // ---- S = Q^T K: 4 fragments of 16x16 (K=32) ----
    f32x4 sfr[4];
#pragma unroll
    for (int jj = 0; jj < 4; ++jj) {
      const int r  = (jj << 3) + (ln >> 1);
      const int ks = (((ln & 1) << 2) | g) ^ ((ln >> 1) & 7);
      bf16x8 kf = *reinterpret_cast<const bf16x8*>(Kb + r * 64 + ks * 8);
      sfr[jj] = __builtin_amdgcn_mfma_f32_16x16x32_bf16(qf, kf, vzero, 0, 0, 0);
    }

    // ---- P = exp(scale*S + rel); per-lane partial row sums ----
#pragma unroll
    for (int v = 0; v < 4; ++v) {
      float p0 = __expf(sfr[0][v] * scale + relA[0 + v]);
      float p1 = __expf(sfr[1][v] * scale + relA[4 + v]);
      float p2 = __expf(sfr[2][v] * scale + relA[8 + v]);
      float p3 = __expf(sfr[3][v] * scale + relA[12 + v]);
      l_lane[v] += (p0 + p1) + (p2 + p3);
      const int prow = ((g << 2) + v) * 72 + ln;    // P transpose via wave-private LDS
      sPw[prow +  0] = f2bf(p0);
      sPw[prow + 16] = f2bf(p1);
      sPw[prow + 32] = f2bf(p2);
      sPw[prow + 48] = f2bf(p3);
    }

    // ---- PV: acc[i][d] += P[i,j] * V[d,j] ----
#pragma unroll
    for (int kc = 0; kc < 2; ++kc) {
      bf16x8 pa = *reinterpret_cast<const bf16x8*>(sPw + ln * 72 + (kc << 5) + (g << 3));
#pragma unroll
      for (int dc = 0; dc < 2; ++dc) {
        const int d  = (dc << 4) + ln;
        const int vs = ((kc << 2) | g) ^ (d & 7);
        bf16x8 vf = *reinterpret_cast<const bf16x8*>(Vb + d * 64 + vs * 8);
        accO[dc] = __builtin_amdgcn_mfma_f32_16x16x32_bf16(pa, vf, accO[dc], 0, 0, 0);
      }
    }

    if (js < 15) {
#pragma unroll
      for (int e = 0; e < 16; ++e) relA[e] = relB[e];
    }
  }
#undef STAGE

  // ---- epilogue: single shuffle-reduce of l, divide, bf16 write [b][n][c] ----
#pragma unroll
  for (int v = 0; v < 4; ++v) {
    float ls = l_lane[v];
    ls += __shfl_xor(ls, 1);
    ls += __shfl_xor(ls, 2);
    ls += __shfl_xor(ls, 4);
    ls += __shfl_xor(ls, 8);
    const float inv = 1.f / ls;
    const size_t row = (size_t)bw * NPIX + i0 + (iw << 4) + (g << 2) + v;
    aout[row * DATTN + (h << 5) + ln]      = f2bf(accO[0][v] * inv);
    aout[row * DATTN + (h << 5) + 16 + ln] = f2bf(accO[1][v] * inv);
  }
}

// ---------------------------------------------------------------------------
// Proj GEMM (MFMA): out[b][o][n] = sum_k Wp[o,k] * A[b][n][k] + bias[o], f32 out.
// ---------------------------------------------------------------------------
__global__ __launch_bounds__(256) void gemm_proj_mfma(const u16* __restrict__ wp,
                                                      const u16* __restrict__ at,
                                                      const float* __restrict__ bias,
                                                      float* __restrict__ out) {
  __shared__ __align__(16) u16 sA[64 * 64];
  __shared__ __align__(16) u16 sB[128 * 64];
  const int t  = threadIdx.x;
  const int w  = t >> 6, l = t & 63, g = l >> 4, ln = l & 15;
  const int n0 = blockIdx.x * 128;
  const int o0 = blockIdx.y * 64;
  const int b  = blockIdx.z;
  const int wm = w >> 1, wn = w & 1;

  const u16* wbase = wp + (size_t)o0 * DATTN;
  const u16* abase = at + ((size_t)b * NPIX + n0) * DATTN;

  f32x4 acc[2][4];
#pragma unroll
  for (int mi = 0; mi < 2; ++mi)
#pragma unroll
    for (int ni = 0; ni < 4; ++ni) acc[mi][ni] = {0.f, 0.f, 0.f, 0.f};

  for (int k0 = 0; k0 < DATTN; k0 += 64) {
#pragma unroll
    for (int i = 0; i < 2; ++i) {
      int chunk = i * 256 + (w << 6) + l;
      gl_lds16(wbase + ((size_t)(chunk >> 3)) * DATTN + k0 + ((chunk & 7) << 3),
               (char*)sA + i * 4096 + (w << 10));
    }
#pragma unroll
    for (int i = 0; i < 4; ++i) {
      int chunk = i * 256 + (w << 6) + l;
      gl_lds16(abase + ((size_t)(chunk >> 3)) * DATTN + k0 + ((chunk & 7) << 3),
               (char*)sB + i * 4096 + (w << 10));
    }
    __syncthreads();
#pragma unroll
    for (int kk = 0; kk < 64; kk += 32) {
      bf16x8 af[2], bfr[4];
#pragma unroll
      for (int mi = 0; mi < 2; ++mi)
        af[mi] = *reinterpret_cast<const bf16x8*>(&sA[((wm << 5) + (mi << 4) + ln) * 64 + kk + (g << 3)]);
#pragma unroll
      for (int ni = 0; ni < 4; ++ni)
        bfr[ni] = *reinterpret_cast<const bf16x8*>(&sB[((wn << 6) + (ni << 4) + ln) * 64 + kk + (g << 3)]);
#pragma unroll
      for (int mi = 0; mi < 2; ++mi)
#pragma unroll
        for (int ni = 0; ni < 4; ++ni)
          acc[mi][ni] = __builtin_amdgcn_mfma_f32_16x16x32_bf16(af[mi], bfr[ni], acc[mi][ni], 0, 0, 0);
    }
    __syncthreads();
  }

#pragma unroll
  for (int mi = 0; mi < 2; ++mi) {
    const int o = o0 + (wm << 5) + (mi << 4) + (g << 2);
    const float b0 = bias[o], b1 = bias[o + 1], b2 = bias[o + 2], b3 = bias[o + 3];
#pragma unroll
    for (int ni = 0; ni < 4; ++ni) {
      const int n = n0 + (wn << 6) + (ni << 4) + ln;
      float* op = &out[((size_t)b * DATTN + o) * NPIX + n];
      op[0]        = acc[mi][ni][0] + b0;
      op[NPIX]     = acc[mi][ni][1] + b1;
      op[2 * NPIX] = acc[mi][ni][2] + b2;
      op[3 * NPIX] = acc[mi][ni][3] + b3;
    }
  }
}

extern "C" void kernel_launch(void* const* d_in, const int* in_sizes, int n_in,
                              void* d_out, int out_size, void* d_ws, size_t ws_size,
                              hipStream_t stream) {
  (void)in_sizes; (void)n_in; (void)out_size; (void)ws_size;
  const float* x      = (const float*)d_in[0];
  const float* w_qkv  = (const float*)d_in[1];
  const float* b_qkv  = (const float*)d_in[2];
  const float* w_proj = (const float*)d_in[3];
  const float* b_proj = (const float*)d_in[4];
  const float* rel    = (const float*)d_in[5];
  float* out = (float*)d_out;

  u16* xt    = (u16*)d_ws;                                   // 4 MB
  u16* wq_bf = xt + (size_t)BATCH * NPIX * CIN;              // 1.5 MB
  u16* wp_bf = wq_bf + (size_t)O_QKV * CIN;                  // 0.5 MB
  u16* qt    = wp_bf + (size_t)DATTN * DATTN;                // 4 MB
  u16* kt    = qt + (size_t)BATCH * HEADS * NPIX * DH;       // 4 MB
  u16* vt    = kt + (size_t)BATCH * HEADS * NPIX * DH;       // 4 MB
  u16* aout  = vt + (size_t)BATCH * HEADS * NPIX * DH;       // 4 MB

  prep_w<<<1024, 256, 0, stream>>>(w_qkv, w_proj, wq_bf, wp_bf);
  prep_x<<<dim3(NPIX / 64, CIN / 64, BATCH), 256, 0, stream>>>(x, xt);
  gemm_qkv_mfma<<<dim3(NPIX / 128, HEADS, BATCH), 256, 0, stream>>>(wq_bf, xt, b_qkv, qt, kt, vt);
  attn_mfma<<<512, 512, 0, stream>>>(qt, kt, vt, rel, aout);
  gemm_proj_mfma<<<dim3(NPIX / 128, DATTN / 64, BATCH), 256, 0, stream>>>(wp_bf, aout, b_proj, out);
}

// Round 5
// 66.184 us; speedup vs baseline: 4.9808x; 1.0725x over previous
//
#include <hip/hip_runtime.h>
#include <cstdint>
#include <cstddef>

#define BATCH 4
#define CIN   512
#define NPIX  1024
#define HEADS 16
#define DH    32
#define DATTN 512
#define O_QKV 1536
#define PPAD  88   // sP row stride in u16 (176B = 11*16B): aligned b64/b128, low bank aliasing

typedef unsigned short u16;
typedef __bf16 bf16x4 __attribute__((ext_vector_type(4)));
typedef __bf16 bf16x8 __attribute__((ext_vector_type(8)));
typedef float  f32x4  __attribute__((ext_vector_type(4)));

typedef const __attribute__((address_space(1))) void g1_t;
typedef __attribute__((address_space(3))) void l3_t;

#if defined(__has_builtin)
#if __has_builtin(__builtin_amdgcn_exp2f)
#define EXP2(x) __builtin_amdgcn_exp2f(x)
#endif
#endif
#ifndef EXP2
#define EXP2(x) __expf((x) * 0.6931471805599453f)
#endif

__device__ __forceinline__ u16 f2bf(float f) {
  unsigned u = __float_as_uint(f);
  u += 0x7fffu + ((u >> 16) & 1u);
  return (u16)(u >> 16);
}

// async global->LDS, 16B per lane; lp must be wave-uniform (HW: base + lane*16)
__device__ __forceinline__ void gl_lds16(const void* gp, void* lp) {
  __builtin_amdgcn_global_load_lds((g1_t*)gp, (l3_t*)lp, 16, 0, 0);
}

// ---------------------------------------------------------------------------
// prep_w: convert w_qkv [1536][512] and w_proj [512][512] f32 -> bf16.
// ---------------------------------------------------------------------------
__global__ __launch_bounds__(256) void prep_w(const float* __restrict__ w1,
                                              const float* __restrict__ w2,
                                              u16* __restrict__ o1,
                                              u16* __restrict__ o2) {
  const int idx = blockIdx.x * 256 + threadIdx.x;   // float4 index
  const int n1 = (O_QKV * CIN) >> 2;                // 196608
  float4 v = (idx < n1) ? reinterpret_cast<const float4*>(w1)[idx]
                        : reinterpret_cast<const float4*>(w2)[idx - n1];
  uint2 pk = make_uint2((unsigned)f2bf(v.x) | ((unsigned)f2bf(v.y) << 16),
                        (unsigned)f2bf(v.z) | ((unsigned)f2bf(v.w) << 16));
  if (idx < n1) reinterpret_cast<uint2*>(o1)[idx] = pk;
  else          reinterpret_cast<uint2*>(o2)[idx - n1] = pk;
}

// ---------------------------------------------------------------------------
// prep_x: x [B][C][N] f32 -> xt [B][N][C] bf16 (tiled 64x64 LDS transpose)
// ---------------------------------------------------------------------------
__global__ __launch_bounds__(256) void prep_x(const float* __restrict__ x,
                                              u16* __restrict__ xt) {
  __shared__ float sT[64][65];
  const int t  = threadIdx.x;
  const int n0 = blockIdx.x * 64;
  const int c0 = blockIdx.y * 64;
  const int b  = blockIdx.z;
  const float* xb = x + ((size_t)b * CIN + c0) * NPIX + n0;
#pragma unroll
  for (int i = 0; i < 4; ++i) {
    int r   = i * 16 + (t >> 4);
    int col = (t & 15) << 2;
    float4 v = *reinterpret_cast<const float4*>(&xb[(size_t)r * NPIX + col]);
    sT[r][col + 0] = v.x; sT[r][col + 1] = v.y;
    sT[r][col + 2] = v.z; sT[r][col + 3] = v.w;
  }
  __syncthreads();
#pragma unroll
  for (int i = 0; i < 2; ++i) {
    int nl = t >> 2;
    int ch = (t & 3) + (i << 2);
    u16 tmp[8];
#pragma unroll
    for (int e = 0; e < 8; ++e) tmp[e] = f2bf(sT[(ch << 3) + e][nl]);
    *reinterpret_cast<uint4*>(&xt[((size_t)b * NPIX + n0 + nl) * CIN + c0 + (ch << 3)]) =
        *reinterpret_cast<uint4*>(tmp);
  }
}

// ---------------------------------------------------------------------------
// QKV GEMM (MFMA): M-tile=96 (one head), N-tile=128, BK=64, 4 waves.
// Epilogue: +bias, bf16; q PRE-SCALED by scale*log2e (attn uses exp2 domain).
// qt/kt [b][h][n][32], vt [b][h][d][n].
// ---------------------------------------------------------------------------
__global__ __launch_bounds__(256) void gemm_qkv_mfma(const u16* __restrict__ wq,
                                                     const u16* __restrict__ xt,
                                                     const float* __restrict__ bias,
                                                     u16* __restrict__ qt,
                                                     u16* __restrict__ kt,
                                                     u16* __restrict__ vt) {
  __shared__ __align__(16) u16 sA[96 * 64];
  __shared__ __align__(16) u16 sB[128 * 64];
  const int t  = threadIdx.x;
  const int w  = t >> 6, l = t & 63, g = l >> 4, ln = l & 15;
  const int n0 = blockIdx.x * 128;
  const int h  = blockIdx.y;
  const int b  = blockIdx.z;
  const int wm = w >> 1, wn = w & 1;

  const u16* wbase = wq + (size_t)h * 96 * CIN;
  const u16* xbase = xt + ((size_t)b * NPIX + n0) * CIN;

  f32x4 acc[3][4];
#pragma unroll
  for (int mi = 0; mi < 3; ++mi)
#pragma unroll
    for (int ni = 0; ni < 4; ++ni) acc[mi][ni] = {0.f, 0.f, 0.f, 0.f};

  for (int k0 = 0; k0 < CIN; k0 += 64) {
#pragma unroll
    for (int i = 0; i < 3; ++i) {
      int chunk = i * 256 + (w << 6) + l;
      gl_lds16(wbase + ((size_t)(chunk >> 3)) * CIN + k0 + ((chunk & 7) << 3),
               (char*)sA + i * 4096 + (w << 10));
    }
#pragma unroll
    for (int i = 0; i < 4; ++i) {
      int chunk = i * 256 + (w << 6) + l;
      gl_lds16(xbase + ((size_t)(chunk >> 3)) * CIN + k0 + ((chunk & 7) << 3),
               (char*)sB + i * 4096 + (w << 10));
    }
    __syncthreads();
#pragma unroll
    for (int kk = 0; kk < 64; kk += 32) {
      bf16x8 af[3], bfr[4];
#pragma unroll
      for (int mi = 0; mi < 3; ++mi)
        af[mi] = *reinterpret_cast<const bf16x8*>(&sA[(48 * wm + 16 * mi + ln) * 64 + kk + (g << 3)]);
#pragma unroll
      for (int ni = 0; ni < 4; ++ni)
        bfr[ni] = *reinterpret_cast<const bf16x8*>(&sB[((wn << 6) + (ni << 4) + ln) * 64 + kk + (g << 3)]);
#pragma unroll
      for (int mi = 0; mi < 3; ++mi)
#pragma unroll
        for (int ni = 0; ni < 4; ++ni)
          acc[mi][ni] = __builtin_amdgcn_mfma_f32_16x16x32_bf16(af[mi], bfr[ni], acc[mi][ni], 0, 0, 0);
    }
    __syncthreads();
  }

  const float QSC = 0.17677669529663687f * 1.4426950408889634f;  // scale*log2e
  const float* bh = bias + h * 96;
#pragma unroll
  for (int mi = 0; mi < 3; ++mi) {
    const int sec = 48 * wm + 16 * mi;
    const int rb  = sec + (g << 2);
    const float b0 = bh[rb + 0], b1 = bh[rb + 1], b2 = bh[rb + 2], b3 = bh[rb + 3];
#pragma unroll
    for (int ni = 0; ni < 4; ++ni) {
      const int n = n0 + (wn << 6) + (ni << 4) + ln;
      f32x4 a = acc[mi][ni];
      float v0 = a[0] + b0, v1 = a[1] + b1, v2 = a[2] + b2, v3 = a[3] + b3;
      if (sec < 32) { v0 *= QSC; v1 *= QSC; v2 *= QSC; v3 *= QSC; }
      u16 e0 = f2bf(v0), e1 = f2bf(v1), e2 = f2bf(v2), e3 = f2bf(v3);
      if (sec < 32) {
        const int d = sec + (g << 2);
        uint2 pk = make_uint2((unsigned)e0 | ((unsigned)e1 << 16),
                              (unsigned)e2 | ((unsigned)e3 << 16));
        *reinterpret_cast<uint2*>(&qt[(((size_t)(b * HEADS + h)) * NPIX + n) * DH + d]) = pk;
      } else if (sec < 64) {
        const int d = sec - 32 + (g << 2);
        uint2 pk = make_uint2((unsigned)e0 | ((unsigned)e1 << 16),
                              (unsigned)e2 | ((unsigned)e3 << 16));
        *reinterpret_cast<uint2*>(&kt[(((size_t)(b * HEADS + h)) * NPIX + n) * DH + d]) = pk;
      } else {
        const int d = sec - 64 + (g << 2);
        u16* vp = &vt[(((size_t)(b * HEADS + h)) * DH + d) * NPIX + n];
        vp[0] = e0; vp[NPIX] = e1; vp[2 * NPIX] = e2; vp[3 * NPIX] = e3;
      }
    }
  }
}

// ---------------------------------------------------------------------------
// MFMA flash attention, 8 waves (2 batches x 4 i-segs), 1 barrier per j-step.
// QK fragments: fragment jj covers j = 4*ln + jj  ->  each lane's 4 P values
// per row are j-contiguous -> single ds_write_b64 per (row, lane).
// K LDS: packed rows r=j>>1 (128B), slot ^= (r&7)^((r>>3)&1) (2-way free for
//   the strided fragment read). V LDS: [32 d][8 slots], slot ^= (d&7).
// P = exp2(S' + rel*log2e), q pre-scaled by scale*log2e in GEMM epilogue.
// ---------------------------------------------------------------------------
__global__ __launch_bounds__(512, 4) void attn_mfma(const u16* __restrict__ qt,
                                                    const u16* __restrict__ kt,
                                                    const u16* __restrict__ vt,
                                                    const float* __restrict__ rel,
                                                    u16* __restrict__ aout) {
  __shared__ __align__(16) u16 sK[2][2 * 2048];   // [buf][2 local batches][32r][8slot][8]
  __shared__ __align__(16) u16 sV[2][2 * 2048];
  __shared__ __align__(16) u16 sP[8][16 * PPAD];  // per-wave P buffer

  const int t  = threadIdx.x;
  const int w  = t >> 6, l = t & 63, g = l >> 4, ln = l & 15;
  // XCD-aware decode: both bp-halves + 2 heads per XCD for L2 reuse
  const int bid = blockIdx.x;
  const int xcd = bid & 7, sl = bid >> 3;          // sl 0..63
  const int h   = (xcd << 1) | (sl >> 5);
  const int i0  = ((sl >> 1) & 15) << 6;
  const int bp  = sl & 1;                           // batch pair
  const int bw  = (bp << 1) | (w >> 2);             // this wave's batch
  const int iw  = w & 3;                            // i-segment
  const float LOG2E = 1.4426950408889634f;

  // Q fragment (pre-scaled by scale*log2e): lane -> row i0+16*iw+ln, k=8g..8g+7
  bf16x8 qf = *reinterpret_cast<const bf16x8*>(
      qt + (((size_t)(bw * HEADS + h)) * NPIX + i0 + (iw << 4) + ln) * DH + (g << 3));

  f32x4 vzero = {0.f, 0.f, 0.f, 0.f};
  f32x4 accO[2] = {vzero, vzero};
  float l_lane[4] = {0.f, 0.f, 0.f, 0.f};

  // staging mapping (constant per thread): 512 16B chunks per buffer half
  const int sc_b  = (bp << 1) | (t >> 8);           // global batch for staging
  const int sc_cb = t & 255;
  const int sc_r  = sc_cb >> 3;
  const int sc_kc = (sc_cb & 7) ^ (sc_r & 7) ^ ((sc_r >> 3) & 1);  // K logical chunk
  const int sc_vc = (sc_cb & 7) ^ (sc_r & 7);                      // V logical chunk
  const u16* ksrc0 = kt + (((size_t)(sc_b * HEADS + h)) * NPIX +
                           ((sc_r << 1) | (sc_kc >> 2))) * DH + ((sc_kc & 3) << 3);
  const u16* vsrc0 = vt + (((size_t)(sc_b * HEADS + h)) * DH + sc_r) * NPIX + (sc_vc << 3);

#define STAGE(js_, p_) do {                                               \
    gl_lds16(ksrc0 + (size_t)(js_) * 2048, (char*)&sK[p_][0] + (w << 10)); \
    gl_lds16(vsrc0 + (size_t)(js_) * 64,   (char*)&sV[p_][0] + (w << 10)); \
  } while (0)

  // rel: lane (g,ln) needs rows i0+16iw+4g+v, cols js*64 + 4ln + (0..3) -> float4
  const float* relp = rel + ((size_t)h * NPIX + i0 + (iw << 4) + (g << 2)) * NPIX + (ln << 2);
  f32x4 relA4[4], relB4[4];
#pragma unroll
  for (int v = 0; v < 4; ++v)
    relA4[v] = *reinterpret_cast<const f32x4*>(relp + (size_t)v * NPIX);

  STAGE(0, 0);

  u16* sPw = &sP[w][0];
  const int lb = w >> 2;                            // local batch index (0/1)

  for (int js = 0; js < 16; ++js) {
    const int p = js & 1;
    __syncthreads();                                // buf p ready; buf p^1 free
    if (js < 15) {
      STAGE(js + 1, p ^ 1);
#pragma unroll
      for (int v = 0; v < 4; ++v)
        relB4[v] = *reinterpret_cast<const f32x4*>(relp + (size_t)v * NPIX + ((js + 1) << 6));
    }

    const u16* Kb = &sK[p][lb << 11];
    const u16* Vb = &sV[p][lb << 11];

    // ---- S' = Q'^T K: fragment jj covers cols j = 4*ln + jj ----
    f32x4 sfr[4];
#pragma unroll
    for (int jj = 0; jj < 4; ++jj) {
      const int r  = (ln << 1) + (jj >> 1);
      const int ks = ((((jj & 1) << 2) | g) ^ (r & 7)) ^ ((r >> 3) & 1);
      bf16x8 kf = *reinterpret_cast<const bf16x8*>(Kb + r * 64 + ks * 8);
      sfr[jj] = __builtin_amdgcn_mfma_f32_16x16x32_bf16(qf, kf, vzero, 0, 0, 0);
    }

    // ---- P = exp2(S' + rel*log2e); contiguous b64 write per row ----
#pragma unroll
    for (int v = 0; v < 4; ++v) {
      float p0 = EXP2(fmaf(relA4[v][0], LOG2E, sfr[0][v]));
      float p1 = EXP2(fmaf(relA4[v][1], LOG2E, sfr[1][v]));
      float p2 = EXP2(fmaf(relA4[v][2], LOG2E, sfr[2][v]));
      float p3 = EXP2(fmaf(relA4[v][3], LOG2E, sfr[3][v]));
      l_lane[v] += (p0 + p1) + (p2 + p3);
      bf16x4 pk;
      pk[0] = (__bf16)p0; pk[1] = (__bf16)p1; pk[2] = (__bf16)p2; pk[3] = (__bf16)p3;
      *reinterpret_cast<bf16x4*>(sPw + ((g << 2) + v) * PPAD + (ln << 2)) = pk;
    }

    // ---- PV: acc[i][d] += P[i,j] * V[d,j] ----
#pragma unroll
    for (int kc = 0; kc < 2; ++kc) {
      bf16x8 pa = *reinterpret_cast<const bf16x8*>(sPw + ln * PPAD + (kc << 5) + (g << 3));
#pragma unroll
      for (int dc = 0; dc < 2; ++dc) {
        const int d  = (dc << 4) + ln;
        const int vs = ((kc << 2) | g) ^ (d & 7);
        bf16x8 vf = *reinterpret_cast<const bf16x8*>(Vb + d * 64 + vs * 8);
        accO[dc] = __builtin_amdgcn_mfma_f32_16x16x32_bf16(pa, vf, accO[dc], 0, 0, 0);
      }
    }

    if (js < 15) {
#pragma unroll
      for (int v = 0; v < 4; ++v) relA4[v] = relB4[v];
    }
  }
#undef STAGE

  // ---- epilogue: single shuffle-reduce of l, divide, bf16 write [b][n][c] ----
#pragma unroll
  for (int v = 0; v < 4; ++v) {
    float ls = l_lane[v];
    ls += __shfl_xor(ls, 1);
    ls += __shfl_xor(ls, 2);
    ls += __shfl_xor(ls, 4);
    ls += __shfl_xor(ls, 8);
    const float inv = 1.f / ls;
    const size_t row = (size_t)bw * NPIX + i0 + (iw << 4) + (g << 2) + v;
    aout[row * DATTN + (h << 5) + ln]      = f2bf(accO[0][v] * inv);
    aout[row * DATTN + (h << 5) + 16 + ln] = f2bf(accO[1][v] * inv);
  }
}

// ---------------------------------------------------------------------------
// Proj GEMM (MFMA): out[b][o][n] = sum_k Wp[o,k] * A[b][n][k] + bias[o], f32 out.
// ---------------------------------------------------------------------------
__global__ __launch_bounds__(256) void gemm_proj_mfma(const u16* __restrict__ wp,
                                                      const u16* __restrict__ at,
                                                      const float* __restrict__ bias,
                                                      float* __restrict__ out) {
  __shared__ __align__(16) u16 sA[64 * 64];
  __shared__ __align__(16) u16 sB[128 * 64];
  const int t  = threadIdx.x;
  const int w  = t >> 6, l = t & 63, g = l >> 4, ln = l & 15;
  const int n0 = blockIdx.x * 128;
  const int o0 = blockIdx.y * 64;
  const int b  = blockIdx.z;
  const int wm = w >> 1, wn = w & 1;

  const u16* wbase = wp + (size_t)o0 * DATTN;
  const u16* abase = at + ((size_t)b * NPIX + n0) * DATTN;

  f32x4 acc[2][4];
#pragma unroll
  for (int mi = 0; mi < 2; ++mi)
#pragma unroll
    for (int ni = 0; ni < 4; ++ni) acc[mi][ni] = {0.f, 0.f, 0.f, 0.f};

  for (int k0 = 0; k0 < DATTN; k0 += 64) {
#pragma unroll
    for (int i = 0; i < 2; ++i) {
      int chunk = i * 256 + (w << 6) + l;
      gl_lds16(wbase + ((size_t)(chunk >> 3)) * DATTN + k0 + ((chunk & 7) << 3),
               (char*)sA + i * 4096 + (w << 10));
    }
#pragma unroll
    for (int i = 0; i < 4; ++i) {
      int chunk = i * 256 + (w << 6) + l;
      gl_lds16(abase + ((size_t)(chunk >> 3)) * DATTN + k0 + ((chunk & 7) << 3),
               (char*)sB + i * 4096 + (w << 10));
    }
    __syncthreads();
#pragma unroll
    for (int kk = 0; kk < 64; kk += 32) {
      bf16x8 af[2], bfr[4];
#pragma unroll
      for (int mi = 0; mi < 2; ++mi)
        af[mi] = *reinterpret_cast<const bf16x8*>(&sA[((wm << 5) + (mi << 4) + ln) * 64 + kk + (g << 3)]);
#pragma unroll
      for (int ni = 0; ni < 4; ++ni)
        bfr[ni] = *reinterpret_cast<const bf16x8*>(&sB[((wn << 6) + (ni << 4) + ln) * 64 + kk + (g << 3)]);
#pragma unroll
      for (int mi = 0; mi < 2; ++mi)
#pragma unroll
        for (int ni = 0; ni < 4; ++ni)
          acc[mi][ni] = __builtin_amdgcn_mfma_f32_16x16x32_bf16(af[mi], bfr[ni], acc[mi][ni], 0, 0, 0);
    }
    __syncthreads();
  }

#pragma unroll
  for (int mi = 0; mi < 2; ++mi) {
    const int o = o0 + (wm << 5) + (mi << 4) + (g << 2);
    const float b0 = bias[o], b1 = bias[o + 1], b2 = bias[o + 2], b3 = bias[o + 3];
#pragma unroll
    for (int ni = 0; ni < 4; ++ni) {
      const int n = n0 + (wn << 6) + (ni << 4) + ln;
      float* op = &out[((size_t)b * DATTN + o) * NPIX + n];
      op[0]        = acc[mi][ni][0] + b0;
      op[NPIX]     = acc[mi][ni][1] + b1;
      op[2 * NPIX] = acc[mi][ni][2] + b2;
      op[3 * NPIX] = acc[mi][ni][3] + b3;
    }
  }
}

extern "C" void kernel_launch(void* const* d_in, const int* in_sizes, int n_in,
                              void* d_out, int out_size, void* d_ws, size_t ws_size,
                              hipStream_t stream) {
  (void)in_sizes; (void)n_in; (void)out_size; (void)ws_size;
  const float* x      = (const float*)d_in[0];
  const float* w_qkv  = (const float*)d_in[1];
  const float* b_qkv  = (const float*)d_in[2];
  const float* w_proj = (const float*)d_in[3];
  const float* b_proj = (const float*)d_in[4];
  const float* rel    = (const float*)d_in[5];
  float* out = (float*)d_out;

  u16* xt    = (u16*)d_ws;                                   // 4 MB
  u16* wq_bf = xt + (size_t)BATCH * NPIX * CIN;              // 1.5 MB
  u16* wp_bf = wq_bf + (size_t)O_QKV * CIN;                  // 0.5 MB
  u16* qt    = wp_bf + (size_t)DATTN * DATTN;                // 4 MB
  u16* kt    = qt + (size_t)BATCH * HEADS * NPIX * DH;       // 4 MB
  u16* vt    = kt + (size_t)BATCH * HEADS * NPIX * DH;       // 4 MB
  u16* aout  = vt + (size_t)BATCH * HEADS * NPIX * DH;       // 4 MB

  prep_w<<<1024, 256, 0, stream>>>(w_qkv, w_proj, wq_bf, wp_bf);
  prep_x<<<dim3(NPIX / 64, CIN / 64, BATCH), 256, 0, stream>>>(x, xt);
  gemm_qkv_mfma<<<dim3(NPIX / 128, HEADS, BATCH), 256, 0, stream>>>(wq_bf, xt, b_qkv, qt, kt, vt);
  attn_mfma<<<512, 512, 0, stream>>>(qt, kt, vt, rel, aout);
  gemm_proj_mfma<<<dim3(NPIX / 128, DATTN / 64, BATCH), 256, 0, stream>>>(wp_bf, aout, b_proj, out);
}